// Round 14
// baseline (972.013 us; speedup 1.0000x reference)
//
#include <hip/hip_runtime.h>
#include <hip/hip_bf16.h>

typedef short short8 __attribute__((ext_vector_type(8)));
typedef float floatx4 __attribute__((ext_vector_type(4)));
typedef float float2v __attribute__((ext_vector_type(2)));
typedef unsigned short ushort_t;
typedef unsigned short ushort4v __attribute__((ext_vector_type(4)));

__device__ __forceinline__ ushort_t f2bf(float v) {
    __hip_bfloat16 h = __float2bfloat16(v);
    return *(ushort_t*)&h;
}
__device__ __forceinline__ float bf2f(ushort_t u) {
    return __uint_as_float(((unsigned)u) << 16);
}

// ---------------- fp8 e4m3 (OCP) pack/unpack ----------------
#if defined(__has_builtin)
#if __has_builtin(__builtin_amdgcn_cvt_pk_f32_fp8) && __has_builtin(__builtin_amdgcn_cvt_pk_fp8_f32)
#define HAVE_FP8_CVT 1
#endif
#endif

__device__ __forceinline__ unsigned enc_fp8(float f) {   // manual: RNE, FTZ, clamp 448
    unsigned t = __float_as_uint(f);
    unsigned s = (t >> 24) & 0x80u;
    unsigned mag = t & 0x7fffffffu;
    if (mag > 0x43E00000u) mag = 0x43E00000u;            // clamp to 448
    mag += 0x7FFFFu + ((mag >> 20) & 1u);                // round-to-nearest-even at bit 20
    int e = (int)(mag >> 20) - 960;                      // rebias 127->7
    unsigned r = (e < 1) ? 0u : (unsigned)e;             // flush subnormals
    return s | r;
}
__device__ __forceinline__ float dec_fp8(unsigned b) {
    unsigned bits = ((b & 0x80u) << 24) | ((b & 0x7fu) << 20);
    return __uint_as_float(bits) * 0x1p120f;
}

__device__ __forceinline__ unsigned pack4_fp8(float a, float b, float c, float d) {
#if HAVE_FP8_CVT
    unsigned v = 0;
    v = __builtin_amdgcn_cvt_pk_fp8_f32(a, b, v, false);
    v = __builtin_amdgcn_cvt_pk_fp8_f32(c, d, v, true);
    return v;
#else
    return enc_fp8(a) | (enc_fp8(b) << 8) | (enc_fp8(c) << 16) | (enc_fp8(d) << 24);
#endif
}
__device__ __forceinline__ float4 unpack4_fp8(unsigned v) {
#if HAVE_FP8_CVT
    float2v lo = __builtin_amdgcn_cvt_pk_f32_fp8(v, false);
    float2v hi = __builtin_amdgcn_cvt_pk_f32_fp8(v, true);
    return make_float4(lo.x, lo.y, hi.x, hi.y);
#else
    return make_float4(dec_fp8(v & 0xFFu), dec_fp8((v >> 8) & 0xFFu),
                       dec_fp8((v >> 16) & 0xFFu), dec_fp8(v >> 24));
#endif
}

// Column permutation (per 64-col block): stored i <-> orig o
//   o = (i&3)*16 + (i>>2)      i = (o&15)*4 + (o>>4)

// ---------------- fused prep: alpha zero + x split + W split + edge count ----------------
template <int NCSHIFT>  // K/32 = 1<<NCSHIFT
__device__ __forceinline__ void wsplit_coal(const float* __restrict__ W,
                                            ushort_t* __restrict__ Bh,
                                            ushort_t* __restrict__ Bl,
                                            int o, bool permK) {
    int j = o & 7;
    int l = (o >> 3) & 63;
    int rest = o >> 9;                 // nt*(K/32) + c
    int nt = rest >> NCSHIFT;
    int c  = rest & ((1 << NCSHIFT) - 1);
    int n  = nt * 16 + (l & 15);
    int ks = c * 32 + (l >> 4) * 8 + j;     // stored k
    int i = ks & 63;
    int ko = permK ? ((ks & ~63) | ((i & 3) << 4) | (i >> 2)) : ks;
    float v = W[(size_t)ko * 256 + n];
    ushort_t h = f2bf(v);
    Bh[o] = h;
    Bl[o] = f2bf(v - bf2f(h));
}

__global__ __launch_bounds__(256) void prep_kernel(const float* __restrict__ X,
                                                   ushort_t* __restrict__ Xhi,
                                                   ushort_t* __restrict__ Xlo,
                                                   int* __restrict__ deg,
                                                   int* __restrict__ bcnt,
                                                   const int* __restrict__ edst,
                                                   int E,
                                                   float* __restrict__ asrcA,
                                                   float* __restrict__ adstA,
                                                   const float* __restrict__ W1,
                                                   const float* __restrict__ W2,
                                                   const float* __restrict__ W3,
                                                   ushort_t* __restrict__ B1h, ushort_t* __restrict__ B1l,
                                                   ushort_t* __restrict__ B2h, ushort_t* __restrict__ B2l,
                                                   ushort_t* __restrict__ B3h, ushort_t* __restrict__ B3l,
                                                   int total, int N) {
    int idx = blockIdx.x * 256 + threadIdx.x;
    if (idx < N) {
        asrcA[idx] = 0.f;
        adstA[idx] = 0.f;
    }
    if (idx < E) {                          // edge count (deg/bcnt pre-zeroed via memset)
        int d = edst[idx];
        atomicAdd(&deg[d], 1);
        atomicAdd(&bcnt[d >> 7], 1);
    }
    const int S1 = 128 * 256, S2 = 256 * 256;
    if (idx < S1) {
        wsplit_coal<2>(W1, B1h, B1l, idx, false);
    } else if (idx < S1 + S2) {
        wsplit_coal<3>(W2, B2h, B2l, idx - S1, true);
    } else if (idx < S1 + 2 * S2) {
        wsplit_coal<3>(W3, B3h, B3l, idx - S1 - S2, true);
    }
    if (idx < total) {
        float v = X[idx];
        ushort_t h = f2bf(v);
        Xhi[idx] = h;
        Xlo[idx] = f2bf(v - bf2f(h));
    }
}

// ---------------- LDS-free MFMA split-bf16 GEMM (64x64/wave, y=2 grid) -------------
// H[N,256](fp8, stored order) = A[N,K] @ W. Lo-planes optional per operand:
// layer0 = (Ahi+Alo)@(Whi+Wlo) 3-term; layers1-2 = Ahi@Whi 1-term (both operands
// already bf16-rounded; the lo refinement is below the noise floor).
template <int NCHUNK, bool ALO, bool BLO>
__global__ __launch_bounds__(256) void gemm_mfma(const ushort_t* __restrict__ Ahi_g,
                                                 const ushort_t* __restrict__ Alo_g,
                                                 const ushort_t* __restrict__ Bthi,
                                                 const ushort_t* __restrict__ Btlo,
                                                 unsigned char* __restrict__ Hb,
                                                 const float* __restrict__ a_src,
                                                 const float* __restrict__ a_dst,
                                                 float* __restrict__ asrc_out,
                                                 float* __restrict__ adst_out,
                                                 int N) {
    constexpr int K = NCHUNK * 32;
    const int tid = threadIdx.x;
    const int wave = tid >> 6, lane = tid & 63;
    const int wr = wave & 1, wc = wave >> 1;
    const int q = lane >> 4, l15 = lane & 15;
    const int rowBase = blockIdx.x * 128;
    const int colBase = blockIdx.y * 128;

    floatx4 acc[4][4];
#pragma unroll
    for (int i = 0; i < 4; ++i)
#pragma unroll
        for (int j = 0; j < 4; ++j) acc[i][j] = (floatx4)0.f;

    size_t aoff[4];
#pragma unroll
    for (int mt = 0; mt < 4; ++mt) {
        int r = rowBase + wr * 64 + mt * 16 + l15;
        if (r > N - 1) r = N - 1;                    // clamp (stores guarded)
        aoff[mt] = (size_t)r * K + q * 8;
    }

    const int ntg = blockIdx.y * 8 + wc * 4;
    const size_t ntstride = (size_t)NCHUNK * 512;
    const ushort_t* bhp = Bthi + (size_t)ntg * ntstride + (size_t)lane * 8;
    const ushort_t* blp = Btlo + (size_t)ntg * ntstride + (size_t)lane * 8;

#pragma unroll
    for (int c = 0; c < NCHUNK; ++c) {
        const int co = c * 32;
        const size_t cb = (size_t)c * 512;
        short8 ah[4], al[4], bh[4], bl[4];
#pragma unroll
        for (int mt = 0; mt < 4; ++mt)
            ah[mt] = *(const short8*)(Ahi_g + aoff[mt] + co);
        if (ALO) {
#pragma unroll
            for (int mt = 0; mt < 4; ++mt)
                al[mt] = *(const short8*)(Alo_g + aoff[mt] + co);
        }
#pragma unroll
        for (int nt = 0; nt < 4; ++nt) {
            bh[nt] = *(const short8*)(bhp + (size_t)nt * ntstride + cb);
            if (BLO) bl[nt] = *(const short8*)(blp + (size_t)nt * ntstride + cb);
        }
#pragma unroll
        for (int mt = 0; mt < 4; ++mt)
#pragma unroll
            for (int nt = 0; nt < 4; ++nt) {
                acc[mt][nt] = __builtin_amdgcn_mfma_f32_16x16x32_bf16(ah[mt], bh[nt], acc[mt][nt], 0, 0, 0);
                if (BLO)
                    acc[mt][nt] = __builtin_amdgcn_mfma_f32_16x16x32_bf16(ah[mt], bl[nt], acc[mt][nt], 0, 0, 0);
                if (ALO)
                    acc[mt][nt] = __builtin_amdgcn_mfma_f32_16x16x32_bf16(al[mt], bh[nt], acc[mt][nt], 0, 0, 0);
            }
    }

    // ---- epilogue: packed 4B fp8 stores (stored order) + alpha atomics ----
    float asv[4], adv[4];
#pragma unroll
    for (int nt = 0; nt < 4; ++nt) {
        int n = colBase + wc * 64 + nt * 16 + l15;   // orig order for alpha
        asv[nt] = a_src[n];
        adv[nt] = a_dst[n];
    }
#pragma unroll
    for (int mt = 0; mt < 4; ++mt) {
#pragma unroll
        for (int reg = 0; reg < 4; ++reg) {
            int grow = rowBase + wr * 64 + mt * 16 + q * 4 + reg;
            float p1 = acc[mt][0][reg] * asv[0] + acc[mt][1][reg] * asv[1] +
                       acc[mt][2][reg] * asv[2] + acc[mt][3][reg] * asv[3];
            float p2 = acc[mt][0][reg] * adv[0] + acc[mt][1][reg] * adv[1] +
                       acc[mt][2][reg] * adv[2] + acc[mt][3][reg] * adv[3];
            if (grow < N) {
                unsigned pk = pack4_fp8(acc[mt][0][reg], acc[mt][1][reg],
                                        acc[mt][2][reg], acc[mt][3][reg]);
                *(unsigned*)(Hb + (size_t)grow * 256 + colBase + wc * 64 + l15 * 4) = pk;
            }
#pragma unroll
            for (int off = 1; off < 16; off <<= 1) {
                p1 += __shfl_xor(p1, off, 64);
                p2 += __shfl_xor(p2, off, 64);
            }
            if (l15 == 0 && grow < N) {
                atomicAdd(&asrc_out[grow], p1);
                atomicAdd(&adst_out[grow], p2);
            }
        }
    }
}

// ---------------- CSR build (scans + bucketed 2-phase scatter) ----------------
__global__ __launch_bounds__(256) void scan1_kernel(const int* __restrict__ deg,
                                                    int* __restrict__ excl,
                                                    int* __restrict__ bsum, int N) {
    __shared__ int tmp[256];
    int tid = threadIdx.x;
    int i = blockIdx.x * 256 + tid;
    int v = (i < N) ? deg[i] : 0;
    tmp[tid] = v;
    __syncthreads();
    for (int off = 1; off < 256; off <<= 1) {
        int t = (tid >= off) ? tmp[tid - off] : 0;
        __syncthreads();
        tmp[tid] += t;
        __syncthreads();
    }
    if (i < N) excl[i] = tmp[tid] - v;
    if (tid == 255) bsum[blockIdx.x] = tmp[255];
}

__global__ __launch_bounds__(256) void scan2_kernel(int* __restrict__ bsum, int nb) {
    __shared__ int tmp[256];
    int tid = threadIdx.x;
    int v = (tid < nb) ? bsum[tid] : 0;
    tmp[tid] = v;
    __syncthreads();
    for (int off = 1; off < 256; off <<= 1) {
        int t = (tid >= off) ? tmp[tid - off] : 0;
        __syncthreads();
        tmp[tid] += t;
        __syncthreads();
    }
    if (tid < nb) bsum[tid] = tmp[tid] - v;
}

__global__ __launch_bounds__(256) void scan3_kernel(const int* __restrict__ excl,
                                                    const int* __restrict__ bsum,
                                                    int* __restrict__ rowptr,
                                                    int* __restrict__ cursor,
                                                    int N, int E) {
    int i = blockIdx.x * 256 + threadIdx.x;
    if (i < N) {
        int v = excl[i] + bsum[blockIdx.x];
        rowptr[i] = v;
        cursor[i] = v;
    }
    if (i == 0) rowptr[N] = E;
}

// single-block exclusive scan over NB bucket counts (NB <= 512)
__global__ __launch_bounds__(512) void bscan_kernel(int* __restrict__ bcnt,
                                                    int* __restrict__ bcur, int nb) {
    __shared__ int tmp[512];
    int tid = threadIdx.x;
    int v = (tid < nb) ? bcnt[tid] : 0;
    tmp[tid] = v;
    __syncthreads();
    for (int off = 1; off < 512; off <<= 1) {
        int t = (tid >= off) ? tmp[tid - off] : 0;
        __syncthreads();
        tmp[tid] += t;
        __syncthreads();
    }
    if (tid < nb) bcur[tid] = tmp[tid] - v;     // exclusive offsets as cursors
}

// phase B: edges -> bucket-ordered pairs (dense contiguous writes per bucket)
__global__ __launch_bounds__(256) void bucket_scatter_kernel(const int* __restrict__ esrc,
                                                             const int* __restrict__ edst,
                                                             int* __restrict__ bcur,
                                                             uint2* __restrict__ ebuf, int E) {
    int i = blockIdx.x * 256 + threadIdx.x;
    if (i < E) {
        int s = esrc[i], d = edst[i];
        int pos = atomicAdd(&bcur[d >> 7], 1);
        ebuf[pos] = make_uint2((unsigned)s, (unsigned)d);
    }
}

// phase C: bucket-ordered pairs -> CSR (writes confined to ~8KB window per bucket)
__global__ __launch_bounds__(256) void final_scatter_kernel(const uint2* __restrict__ ebuf,
                                                            int* __restrict__ cursor,
                                                            int* __restrict__ csr_src, int E) {
    int i = blockIdx.x * 256 + threadIdx.x;
    if (i < E) {
        uint2 e = ebuf[i];
        int pos = atomicAdd(&cursor[e.y], 1);
        csr_src[pos] = (int)e.x;
    }
}

// ---------------- fused GAT aggregation: one wave per dst node (fp8 gather) ----------------
__global__ __launch_bounds__(256) void gat_fused_kernel(const unsigned char* __restrict__ hb,
                                                        const float* __restrict__ asrc,
                                                        const float* __restrict__ adst,
                                                        const int* __restrict__ rowptr,
                                                        const int* __restrict__ csr_src,
                                                        const float* __restrict__ bias,
                                                        ushort_t* __restrict__ ohi,
                                                        float* __restrict__ asrc_next,
                                                        float* __restrict__ adst_next,
                                                        int N) {
    int wave = threadIdx.x >> 6;
    int lane = threadIdx.x & 63;
    int d = blockIdx.x * 4 + wave;
    if (d >= N) return;

    if (lane == 0) {
        asrc_next[d] = 0.f;
        adst_next[d] = 0.f;
    }

    const float* bb = bias + (lane >> 4) * 64 + (lane & 15);
    float b0 = bb[0], b1 = bb[16], b2 = bb[32], b3 = bb[48];

    float ad = adst[d];
    float es = asrc[d] + ad;
    es = es >= 0.f ? es : 0.2f * es;
    float m = es;
    float s = 1.0f;
    float4 acc = unpack4_fp8(*(const unsigned*)(hb + (size_t)d * 256 + lane * 4));

    int beg = rowptr[d], end = rowptr[d + 1];
    for (int base = beg; base < end; base += 64) {
        int cnt = min(64, end - base);
        int srci = 0;
        float e = -1e30f;
        if (lane < cnt) {
            srci = csr_src[base + lane];
            float v = asrc[srci] + ad;
            e = v >= 0.f ? v : 0.2f * v;
        }
        float cm = e;
#pragma unroll
        for (int off = 32; off > 0; off >>= 1) cm = fmaxf(cm, __shfl_xor(cm, off, 64));
        float mnew = fmaxf(m, cm);
        float scale = __expf(m - mnew);
        m = mnew;

        float p = __expf(e - m);            // e=-1e30 lanes -> 0
        float ps = p;
#pragma unroll
        for (int off = 32; off > 0; off >>= 1) ps += __shfl_xor(ps, off, 64);
        s = s * scale + ps;
        acc.x *= scale; acc.y *= scale; acc.z *= scale; acc.w *= scale;

        int j = 0;
        for (; j + 4 <= cnt; j += 4) {
            float p0 = __shfl(p, j, 64),     p1 = __shfl(p, j + 1, 64);
            float p2 = __shfl(p, j + 2, 64), p3 = __shfl(p, j + 3, 64);
            int s0 = __shfl(srci, j, 64),     s1i = __shfl(srci, j + 1, 64);
            int s2i = __shfl(srci, j + 2, 64), s3i = __shfl(srci, j + 3, 64);
            unsigned v0 = *(const unsigned*)(hb + (size_t)s0 * 256 + lane * 4);
            unsigned v1 = *(const unsigned*)(hb + (size_t)s1i * 256 + lane * 4);
            unsigned v2 = *(const unsigned*)(hb + (size_t)s2i * 256 + lane * 4);
            unsigned v3 = *(const unsigned*)(hb + (size_t)s3i * 256 + lane * 4);
            float4 hv0 = unpack4_fp8(v0);
            float4 hv1 = unpack4_fp8(v1);
            float4 hv2 = unpack4_fp8(v2);
            float4 hv3 = unpack4_fp8(v3);
            acc.x += p0 * hv0.x + p1 * hv1.x + p2 * hv2.x + p3 * hv3.x;
            acc.y += p0 * hv0.y + p1 * hv1.y + p2 * hv2.y + p3 * hv3.y;
            acc.z += p0 * hv0.z + p1 * hv1.z + p2 * hv2.z + p3 * hv3.z;
            acc.w += p0 * hv0.w + p1 * hv1.w + p2 * hv2.w + p3 * hv3.w;
        }
        for (; j < cnt; ++j) {
            float pj = __shfl(p, j, 64);
            int sj = __shfl(srci, j, 64);
            float4 hv = unpack4_fp8(*(const unsigned*)(hb + (size_t)sj * 256 + lane * 4));
            acc.x += pj * hv.x; acc.y += pj * hv.y; acc.z += pj * hv.z; acc.w += pj * hv.w;
        }
    }
    float inv = 1.0f / s;
    float ox = fmaxf(acc.x * inv + b0, 0.f);
    float oy = fmaxf(acc.y * inv + b1, 0.f);
    float oz = fmaxf(acc.z * inv + b2, 0.f);
    float ow = fmaxf(acc.w * inv + b3, 0.f);
    ushort4v hv;
    hv.x = f2bf(ox); hv.y = f2bf(oy); hv.z = f2bf(oz); hv.w = f2bf(ow);
    *(ushort4v*)(ohi + (size_t)d * 256 + lane * 4) = hv;
}

// ---------------- fused mean pool + FC + softmax (batch is sorted) ----------------
__device__ __forceinline__ int lower_bound_i(const int* __restrict__ a, int n, int v) {
    int lo = 0, hi = n;
    while (lo < hi) {
        int mid = (lo + hi) >> 1;
        if (a[mid] < v) lo = mid + 1; else hi = mid;
    }
    return lo;
}

__global__ __launch_bounds__(256) void pool_fc_kernel(const ushort_t* __restrict__ hhi,
                                                      const int* __restrict__ batch,
                                                      int N,
                                                      const float* __restrict__ Wfc,
                                                      const float* __restrict__ bfc,
                                                      float* __restrict__ out) {
    __shared__ float red0[256];
    __shared__ float red1[256];
    int g = blockIdx.x;
    int c = threadIdx.x;                       // stored col
    int i = c & 63;
    int o = (c & ~63) | ((i & 3) << 4) | (i >> 2);   // orig col
    int beg = lower_bound_i(batch, N, g);
    int end = lower_bound_i(batch, N, g + 1);
    float sum = 0.f;
    for (int n = beg; n < end; ++n)
        sum += bf2f(hhi[(size_t)n * 256 + c]);
    float cnt = (float)(end - beg);
    float v = sum / fmaxf(cnt, 1.0f);
    red0[c] = v * Wfc[o * 2 + 0];
    red1[c] = v * Wfc[o * 2 + 1];
    __syncthreads();
    for (int off = 128; off > 0; off >>= 1) {
        if (c < off) {
            red0[c] += red0[c + off];
            red1[c] += red1[c + off];
        }
        __syncthreads();
    }
    if (c == 0) {
        float l0 = red0[0] + bfc[0];
        float l1 = red1[0] + bfc[1];
        float mx = fmaxf(l0, l1);
        float e0 = expf(l0 - mx), e1 = expf(l1 - mx);
        float s = e0 + e1;
        out[g * 2 + 0] = e0 / s;
        out[g * 2 + 1] = e1 / s;
    }
}

// ---------------- launch ----------------
extern "C" void kernel_launch(void* const* d_in, const int* in_sizes, int n_in,
                              void* d_out, int out_size, void* d_ws, size_t ws_size,
                              hipStream_t stream) {
    const float* x    = (const float*)d_in[0];
    const int*   eidx = (const int*)d_in[1];
    const int*   batch= (const int*)d_in[2];
    const float* Wl[3]  = {(const float*)d_in[3], (const float*)d_in[7],  (const float*)d_in[11]};
    const float* asl[3] = {(const float*)d_in[4], (const float*)d_in[8],  (const float*)d_in[12]};
    const float* adl[3] = {(const float*)d_in[5], (const float*)d_in[9],  (const float*)d_in[13]};
    const float* bl[3]  = {(const float*)d_in[6], (const float*)d_in[10], (const float*)d_in[14]};
    const float* Wfc = (const float*)d_in[15];
    const float* bfc = (const float*)d_in[16];
    float* out = (float*)d_out;

    const int N   = in_sizes[2];
    const int E   = in_sizes[1] / 2;
    const int DIN = in_sizes[0] / N;   // 128
    const int DH  = 256;
    const int G   = 512;
    const int NB  = (N + 127) >> 7;    // dst buckets of 128 nodes
    const int* esrc = eidx;
    const int* edst = eidx + E;

    char* ws = (char*)d_ws;
    size_t off = 0;
    const size_t featHalf = (size_t)N * DH * sizeof(ushort_t);         // 25.6 MB
    unsigned char* hb = (unsigned char*)(ws + off); off += (size_t)N * DH;  // fp8, 12.8 MB
    ushort_t* ghi    = (ushort_t*)(ws + off); off += featHalf;         // gat out (bf16, stored order)
    ushort_t* xhi    = (ushort_t*)(ws + off); off += (size_t)N * DIN * sizeof(ushort_t);
    ushort_t* xlo    = (ushort_t*)(ws + off); off += (size_t)N * DIN * sizeof(ushort_t);
    float*    asA    = (float*)(ws + off); off += (size_t)N * sizeof(float);
    float*    adA    = (float*)(ws + off); off += (size_t)N * sizeof(float);
    float*    asB    = (float*)(ws + off); off += (size_t)N * sizeof(float);
    float*    adB    = (float*)(ws + off); off += (size_t)N * sizeof(float);
    int*      deg    = (int*)(ws + off);   off += (size_t)N * sizeof(int);
    int*      excl   = (int*)(ws + off);   off += (size_t)N * sizeof(int);
    int*      rowptr = (int*)(ws + off);   off += (size_t)(N + 1) * sizeof(int);
    int*      cursor = (int*)(ws + off);   off += (size_t)N * sizeof(int);
    int*      bsum   = (int*)(ws + off);   off += 1024;
    int*      bcnt   = (int*)(ws + off);   off += 2048;
    int*      bcur   = (int*)(ws + off);   off += 2048;
    int*      csrsrc = (int*)(ws + off);   off += (size_t)E * sizeof(int);
    uint2*    ebuf   = (uint2*)(ws + off); off += (size_t)E * sizeof(uint2);
    ushort_t* B1h    = (ushort_t*)(ws + off); off += (size_t)128 * 256 * sizeof(ushort_t);
    ushort_t* B1l    = (ushort_t*)(ws + off); off += (size_t)128 * 256 * sizeof(ushort_t);
    ushort_t* B2h    = (ushort_t*)(ws + off); off += (size_t)256 * 256 * sizeof(ushort_t);
    ushort_t* B2l    = (ushort_t*)(ws + off); off += (size_t)256 * 256 * sizeof(ushort_t);
    ushort_t* B3h    = (ushort_t*)(ws + off); off += (size_t)256 * 256 * sizeof(ushort_t);
    ushort_t* B3l    = (ushort_t*)(ws + off); off += (size_t)256 * 256 * sizeof(ushort_t);

    const int nbN = (N + 255) / 256;

    // ---- zero deg/bcnt, then prep (alpha zero + splits + edge count) ----
    hipMemsetAsync(deg, 0, (size_t)N * sizeof(int), stream);
    hipMemsetAsync(bcnt, 0, (size_t)NB * sizeof(int), stream);
    prep_kernel<<<((size_t)N * DIN + 255) / 256, 256, 0, stream>>>(
        x, xhi, xlo, deg, bcnt, edst, E, asA, adA, Wl[0], Wl[1], Wl[2],
        B1h, B1l, B2h, B2l, B3h, B3l, N * DIN, N);

    // ---- CSR: node scans + bucket scan + 2-phase scatter ----
    scan1_kernel<<<nbN, 256, 0, stream>>>(deg, excl, bsum, N);
    scan2_kernel<<<1, 256, 0, stream>>>(bsum, nbN);
    scan3_kernel<<<nbN, 256, 0, stream>>>(excl, bsum, rowptr, cursor, N, E);
    bscan_kernel<<<1, 512, 0, stream>>>(bcnt, bcur, NB);
    bucket_scatter_kernel<<<(E + 255) / 256, 256, 0, stream>>>(esrc, edst, bcur, ebuf, E);
    final_scatter_kernel<<<(E + 255) / 256, 256, 0, stream>>>(ebuf, cursor, csrsrc, E);

    const ushort_t* Bh[3]  = {B1h, B2h, B3h};
    const ushort_t* Blp[3] = {B1l, B2l, B3l};
    float* asCur[3] = {asA, asB, asA};
    float* adCur[3] = {adA, adB, adA};
    float* asNext[3] = {asB, asA, asB};   // zeroed by gat of this layer
    float* adNext[3] = {adB, adA, adB};

    dim3 ggrid((N + 127) / 128, 2);
    for (int layer = 0; layer < 3; ++layer) {
        if (layer == 0) {
            gemm_mfma<4, true, true><<<ggrid, 256, 0, stream>>>(xhi, xlo, Bh[0], Blp[0], hb,
                                                                asl[0], adl[0], asCur[0], adCur[0], N);
        } else {
            gemm_mfma<8, false, false><<<ggrid, 256, 0, stream>>>(ghi, nullptr, Bh[layer], Blp[layer], hb,
                                                                  asl[layer], adl[layer],
                                                                  asCur[layer], adCur[layer], N);
        }

        gat_fused_kernel<<<(N + 3) / 4, 256, 0, stream>>>(hb, asCur[layer], adCur[layer],
                                                          rowptr, csrsrc, bl[layer], ghi,
                                                          asNext[layer], adNext[layer], N);
    }

    pool_fc_kernel<<<G, 256, 0, stream>>>(ghi, batch, N, Wfc, bfc, out);
}

// Round 15
// 435.780 us; speedup vs baseline: 2.2305x; 2.2305x over previous
//
#include <hip/hip_runtime.h>
#include <hip/hip_bf16.h>

typedef short short8 __attribute__((ext_vector_type(8)));
typedef float floatx4 __attribute__((ext_vector_type(4)));
typedef float float2v __attribute__((ext_vector_type(2)));
typedef unsigned short ushort_t;
typedef unsigned short ushort4v __attribute__((ext_vector_type(4)));

__device__ __forceinline__ ushort_t f2bf(float v) {
    __hip_bfloat16 h = __float2bfloat16(v);
    return *(ushort_t*)&h;
}
__device__ __forceinline__ float bf2f(ushort_t u) {
    return __uint_as_float(((unsigned)u) << 16);
}

// ---------------- fp8 e4m3 (OCP) pack/unpack ----------------
#if defined(__has_builtin)
#if __has_builtin(__builtin_amdgcn_cvt_pk_f32_fp8) && __has_builtin(__builtin_amdgcn_cvt_pk_fp8_f32)
#define HAVE_FP8_CVT 1
#endif
#endif

__device__ __forceinline__ unsigned enc_fp8(float f) {   // manual: RNE, FTZ, clamp 448
    unsigned t = __float_as_uint(f);
    unsigned s = (t >> 24) & 0x80u;
    unsigned mag = t & 0x7fffffffu;
    if (mag > 0x43E00000u) mag = 0x43E00000u;            // clamp to 448
    mag += 0x7FFFFu + ((mag >> 20) & 1u);                // round-to-nearest-even at bit 20
    int e = (int)(mag >> 20) - 960;                      // rebias 127->7
    unsigned r = (e < 1) ? 0u : (unsigned)e;             // flush subnormals
    return s | r;
}
__device__ __forceinline__ float dec_fp8(unsigned b) {
    unsigned bits = ((b & 0x80u) << 24) | ((b & 0x7fu) << 20);
    return __uint_as_float(bits) * 0x1p120f;
}

__device__ __forceinline__ unsigned pack4_fp8(float a, float b, float c, float d) {
#if HAVE_FP8_CVT
    unsigned v = 0;
    v = __builtin_amdgcn_cvt_pk_fp8_f32(a, b, v, false);
    v = __builtin_amdgcn_cvt_pk_fp8_f32(c, d, v, true);
    return v;
#else
    return enc_fp8(a) | (enc_fp8(b) << 8) | (enc_fp8(c) << 16) | (enc_fp8(d) << 24);
#endif
}
__device__ __forceinline__ float4 unpack4_fp8(unsigned v) {
#if HAVE_FP8_CVT
    float2v lo = __builtin_amdgcn_cvt_pk_f32_fp8(v, false);
    float2v hi = __builtin_amdgcn_cvt_pk_f32_fp8(v, true);
    return make_float4(lo.x, lo.y, hi.x, hi.y);
#else
    return make_float4(dec_fp8(v & 0xFFu), dec_fp8((v >> 8) & 0xFFu),
                       dec_fp8((v >> 16) & 0xFFu), dec_fp8(v >> 24));
#endif
}

// Column permutation (per 64-col block): stored i <-> orig o
//   o = (i&3)*16 + (i>>2)      i = (o&15)*4 + (o>>4)

// ---------------- fused prep: deg/alpha zero + x split + all-W split (output-coalesced) --------
template <int NCSHIFT>  // K/32 = 1<<NCSHIFT
__device__ __forceinline__ void wsplit_coal(const float* __restrict__ W,
                                            ushort_t* __restrict__ Bh,
                                            ushort_t* __restrict__ Bl,
                                            int o, bool permK) {
    int j = o & 7;
    int l = (o >> 3) & 63;
    int rest = o >> 9;                 // nt*(K/32) + c
    int nt = rest >> NCSHIFT;
    int c  = rest & ((1 << NCSHIFT) - 1);
    int n  = nt * 16 + (l & 15);
    int ks = c * 32 + (l >> 4) * 8 + j;     // stored k
    int i = ks & 63;
    int ko = permK ? ((ks & ~63) | ((i & 3) << 4) | (i >> 2)) : ks;
    float v = W[(size_t)ko * 256 + n];
    ushort_t h = f2bf(v);
    Bh[o] = h;
    Bl[o] = f2bf(v - bf2f(h));
}

__global__ __launch_bounds__(256) void prep_kernel(const float* __restrict__ X,
                                                   ushort_t* __restrict__ Xhi,
                                                   ushort_t* __restrict__ Xlo,
                                                   int* __restrict__ deg,
                                                   float* __restrict__ asrcA,
                                                   float* __restrict__ adstA,
                                                   const float* __restrict__ W1,
                                                   const float* __restrict__ W2,
                                                   const float* __restrict__ W3,
                                                   ushort_t* __restrict__ B1h, ushort_t* __restrict__ B1l,
                                                   ushort_t* __restrict__ B2h, ushort_t* __restrict__ B2l,
                                                   ushort_t* __restrict__ B3h, ushort_t* __restrict__ B3l,
                                                   int total, int N) {
    int idx = blockIdx.x * 256 + threadIdx.x;
    if (idx < N) {
        deg[idx] = 0;
        asrcA[idx] = 0.f;
        adstA[idx] = 0.f;
    }
    const int S1 = 128 * 256, S2 = 256 * 256;
    if (idx < S1) {
        wsplit_coal<2>(W1, B1h, B1l, idx, false);
    } else if (idx < S1 + S2) {
        wsplit_coal<3>(W2, B2h, B2l, idx - S1, true);
    } else if (idx < S1 + 2 * S2) {
        wsplit_coal<3>(W3, B3h, B3l, idx - S1 - S2, true);
    }
    if (idx < total) {
        float v = X[idx];
        ushort_t h = f2bf(v);
        Xhi[idx] = h;
        Xlo[idx] = f2bf(v - bf2f(h));
    }
}

// ---------------- LDS-free MFMA split-bf16 GEMM (64x64/wave, y=2 grid) -------------
// H[N,256](fp8, stored order) = A[N,K] @ W. Lo-planes optional per operand:
// layer0 = (Ahi+Alo)@(Whi+Wlo) 3-term; layers1-2 = Ahi@Whi 1-term (A=ghi is already
// bf16-rounded; W-lo refinement is below that noise floor — verified R14: absmax
// unchanged at 0.00390625 with 1-term).
template <int NCHUNK, bool ALO, bool BLO>
__global__ __launch_bounds__(256) void gemm_mfma(const ushort_t* __restrict__ Ahi_g,
                                                 const ushort_t* __restrict__ Alo_g,
                                                 const ushort_t* __restrict__ Bthi,
                                                 const ushort_t* __restrict__ Btlo,
                                                 unsigned char* __restrict__ Hb,
                                                 const float* __restrict__ a_src,
                                                 const float* __restrict__ a_dst,
                                                 float* __restrict__ asrc_out,
                                                 float* __restrict__ adst_out,
                                                 int N) {
    constexpr int K = NCHUNK * 32;
    const int tid = threadIdx.x;
    const int wave = tid >> 6, lane = tid & 63;
    const int wr = wave & 1, wc = wave >> 1;
    const int q = lane >> 4, l15 = lane & 15;
    const int rowBase = blockIdx.x * 128;
    const int colBase = blockIdx.y * 128;

    floatx4 acc[4][4];
#pragma unroll
    for (int i = 0; i < 4; ++i)
#pragma unroll
        for (int j = 0; j < 4; ++j) acc[i][j] = (floatx4)0.f;

    size_t aoff[4];
#pragma unroll
    for (int mt = 0; mt < 4; ++mt) {
        int r = rowBase + wr * 64 + mt * 16 + l15;
        if (r > N - 1) r = N - 1;                    // clamp (stores guarded)
        aoff[mt] = (size_t)r * K + q * 8;
    }

    const int ntg = blockIdx.y * 8 + wc * 4;
    const size_t ntstride = (size_t)NCHUNK * 512;
    const ushort_t* bhp = Bthi + (size_t)ntg * ntstride + (size_t)lane * 8;
    const ushort_t* blp = Btlo + (size_t)ntg * ntstride + (size_t)lane * 8;

#pragma unroll
    for (int c = 0; c < NCHUNK; ++c) {
        const int co = c * 32;
        const size_t cb = (size_t)c * 512;
        short8 ah[4], al[4], bh[4], bl[4];
#pragma unroll
        for (int mt = 0; mt < 4; ++mt)
            ah[mt] = *(const short8*)(Ahi_g + aoff[mt] + co);
        if (ALO) {
#pragma unroll
            for (int mt = 0; mt < 4; ++mt)
                al[mt] = *(const short8*)(Alo_g + aoff[mt] + co);
        }
#pragma unroll
        for (int nt = 0; nt < 4; ++nt) {
            bh[nt] = *(const short8*)(bhp + (size_t)nt * ntstride + cb);
            if (BLO) bl[nt] = *(const short8*)(blp + (size_t)nt * ntstride + cb);
        }
#pragma unroll
        for (int mt = 0; mt < 4; ++mt)
#pragma unroll
            for (int nt = 0; nt < 4; ++nt) {
                acc[mt][nt] = __builtin_amdgcn_mfma_f32_16x16x32_bf16(ah[mt], bh[nt], acc[mt][nt], 0, 0, 0);
                if (BLO)
                    acc[mt][nt] = __builtin_amdgcn_mfma_f32_16x16x32_bf16(ah[mt], bl[nt], acc[mt][nt], 0, 0, 0);
                if (ALO)
                    acc[mt][nt] = __builtin_amdgcn_mfma_f32_16x16x32_bf16(al[mt], bh[nt], acc[mt][nt], 0, 0, 0);
            }
    }

    // ---- epilogue: packed 4B fp8 stores (stored order) + alpha atomics ----
    float asv[4], adv[4];
#pragma unroll
    for (int nt = 0; nt < 4; ++nt) {
        int n = colBase + wc * 64 + nt * 16 + l15;   // orig order for alpha
        asv[nt] = a_src[n];
        adv[nt] = a_dst[n];
    }
#pragma unroll
    for (int mt = 0; mt < 4; ++mt) {
#pragma unroll
        for (int reg = 0; reg < 4; ++reg) {
            int grow = rowBase + wr * 64 + mt * 16 + q * 4 + reg;
            float p1 = acc[mt][0][reg] * asv[0] + acc[mt][1][reg] * asv[1] +
                       acc[mt][2][reg] * asv[2] + acc[mt][3][reg] * asv[3];
            float p2 = acc[mt][0][reg] * adv[0] + acc[mt][1][reg] * adv[1] +
                       acc[mt][2][reg] * adv[2] + acc[mt][3][reg] * adv[3];
            if (grow < N) {
                unsigned pk = pack4_fp8(acc[mt][0][reg], acc[mt][1][reg],
                                        acc[mt][2][reg], acc[mt][3][reg]);
                *(unsigned*)(Hb + (size_t)grow * 256 + colBase + wc * 64 + l15 * 4) = pk;
            }
#pragma unroll
            for (int off = 1; off < 16; off <<= 1) {
                p1 += __shfl_xor(p1, off, 64);
                p2 += __shfl_xor(p2, off, 64);
            }
            if (l15 == 0 && grow < N) {
                atomicAdd(&asrc_out[grow], p1);
                atomicAdd(&adst_out[grow], p2);
            }
        }
    }
}

// ---------------- CSR build ----------------
__global__ __launch_bounds__(256) void count_kernel(const int* __restrict__ edst,
                                                    int* __restrict__ deg, int E) {
    int i = blockIdx.x * 256 + threadIdx.x;
    if (i < E) atomicAdd(&deg[edst[i]], 1);
}

__global__ __launch_bounds__(256) void scan1_kernel(const int* __restrict__ deg,
                                                    int* __restrict__ excl,
                                                    int* __restrict__ bsum, int N) {
    __shared__ int tmp[256];
    int tid = threadIdx.x;
    int i = blockIdx.x * 256 + tid;
    int v = (i < N) ? deg[i] : 0;
    tmp[tid] = v;
    __syncthreads();
    for (int off = 1; off < 256; off <<= 1) {
        int t = (tid >= off) ? tmp[tid - off] : 0;
        __syncthreads();
        tmp[tid] += t;
        __syncthreads();
    }
    if (i < N) excl[i] = tmp[tid] - v;
    if (tid == 255) bsum[blockIdx.x] = tmp[255];
}

__global__ __launch_bounds__(256) void scan2_kernel(int* __restrict__ bsum, int nb) {
    __shared__ int tmp[256];
    int tid = threadIdx.x;
    int v = (tid < nb) ? bsum[tid] : 0;
    tmp[tid] = v;
    __syncthreads();
    for (int off = 1; off < 256; off <<= 1) {
        int t = (tid >= off) ? tmp[tid - off] : 0;
        __syncthreads();
        tmp[tid] += t;
        __syncthreads();
    }
    if (tid < nb) bsum[tid] = tmp[tid] - v;
}

__global__ __launch_bounds__(256) void scan3_kernel(const int* __restrict__ excl,
                                                    const int* __restrict__ bsum,
                                                    int* __restrict__ rowptr,
                                                    int* __restrict__ cursor,
                                                    int N, int E) {
    int i = blockIdx.x * 256 + threadIdx.x;
    if (i < N) {
        int v = excl[i] + bsum[blockIdx.x];
        rowptr[i] = v;
        cursor[i] = v;
    }
    if (i == 0) rowptr[N] = E;
}

__global__ __launch_bounds__(256) void scatter_kernel(const int* __restrict__ esrc,
                                                      const int* __restrict__ edst,
                                                      int* __restrict__ cursor,
                                                      int* __restrict__ csr_src, int E) {
    int i = blockIdx.x * 256 + threadIdx.x;
    if (i < E) {
        int d = edst[i];
        int pos = atomicAdd(&cursor[d], 1);
        csr_src[pos] = esrc[i];
    }
}

// ---------------- fused GAT aggregation: one wave per dst node (fp8 gather) ----------------
__global__ __launch_bounds__(256) void gat_fused_kernel(const unsigned char* __restrict__ hb,
                                                        const float* __restrict__ asrc,
                                                        const float* __restrict__ adst,
                                                        const int* __restrict__ rowptr,
                                                        const int* __restrict__ csr_src,
                                                        const float* __restrict__ bias,
                                                        ushort_t* __restrict__ ohi,
                                                        float* __restrict__ asrc_next,
                                                        float* __restrict__ adst_next,
                                                        int N) {
    int wave = threadIdx.x >> 6;
    int lane = threadIdx.x & 63;
    int d = blockIdx.x * 4 + wave;
    if (d >= N) return;

    if (lane == 0) {
        asrc_next[d] = 0.f;
        adst_next[d] = 0.f;
    }

    const float* bb = bias + (lane >> 4) * 64 + (lane & 15);
    float b0 = bb[0], b1 = bb[16], b2 = bb[32], b3 = bb[48];

    float ad = adst[d];
    float es = asrc[d] + ad;
    es = es >= 0.f ? es : 0.2f * es;
    float m = es;
    float s = 1.0f;
    float4 acc = unpack4_fp8(*(const unsigned*)(hb + (size_t)d * 256 + lane * 4));

    int beg = rowptr[d], end = rowptr[d + 1];
    for (int base = beg; base < end; base += 64) {
        int cnt = min(64, end - base);
        int srci = 0;
        float e = -1e30f;
        if (lane < cnt) {
            srci = csr_src[base + lane];
            float v = asrc[srci] + ad;
            e = v >= 0.f ? v : 0.2f * v;
        }
        float cm = e;
#pragma unroll
        for (int off = 32; off > 0; off >>= 1) cm = fmaxf(cm, __shfl_xor(cm, off, 64));
        float mnew = fmaxf(m, cm);
        float scale = __expf(m - mnew);
        m = mnew;

        float p = __expf(e - m);            // e=-1e30 lanes -> 0
        float ps = p;
#pragma unroll
        for (int off = 32; off > 0; off >>= 1) ps += __shfl_xor(ps, off, 64);
        s = s * scale + ps;
        acc.x *= scale; acc.y *= scale; acc.z *= scale; acc.w *= scale;

        int j = 0;
        for (; j + 4 <= cnt; j += 4) {
            float p0 = __shfl(p, j, 64),     p1 = __shfl(p, j + 1, 64);
            float p2 = __shfl(p, j + 2, 64), p3 = __shfl(p, j + 3, 64);
            int s0 = __shfl(srci, j, 64),     s1i = __shfl(srci, j + 1, 64);
            int s2i = __shfl(srci, j + 2, 64), s3i = __shfl(srci, j + 3, 64);
            unsigned v0 = *(const unsigned*)(hb + (size_t)s0 * 256 + lane * 4);
            unsigned v1 = *(const unsigned*)(hb + (size_t)s1i * 256 + lane * 4);
            unsigned v2 = *(const unsigned*)(hb + (size_t)s2i * 256 + lane * 4);
            unsigned v3 = *(const unsigned*)(hb + (size_t)s3i * 256 + lane * 4);
            float4 hv0 = unpack4_fp8(v0);
            float4 hv1 = unpack4_fp8(v1);
            float4 hv2 = unpack4_fp8(v2);
            float4 hv3 = unpack4_fp8(v3);
            acc.x += p0 * hv0.x + p1 * hv1.x + p2 * hv2.x + p3 * hv3.x;
            acc.y += p0 * hv0.y + p1 * hv1.y + p2 * hv2.y + p3 * hv3.y;
            acc.z += p0 * hv0.z + p1 * hv1.z + p2 * hv2.z + p3 * hv3.z;
            acc.w += p0 * hv0.w + p1 * hv1.w + p2 * hv2.w + p3 * hv3.w;
        }
        for (; j < cnt; ++j) {
            float pj = __shfl(p, j, 64);
            int sj = __shfl(srci, j, 64);
            float4 hv = unpack4_fp8(*(const unsigned*)(hb + (size_t)sj * 256 + lane * 4));
            acc.x += pj * hv.x; acc.y += pj * hv.y; acc.z += pj * hv.z; acc.w += pj * hv.w;
        }
    }
    float inv = 1.0f / s;
    float ox = fmaxf(acc.x * inv + b0, 0.f);
    float oy = fmaxf(acc.y * inv + b1, 0.f);
    float oz = fmaxf(acc.z * inv + b2, 0.f);
    float ow = fmaxf(acc.w * inv + b3, 0.f);
    ushort4v hv;
    hv.x = f2bf(ox); hv.y = f2bf(oy); hv.z = f2bf(oz); hv.w = f2bf(ow);
    *(ushort4v*)(ohi + (size_t)d * 256 + lane * 4) = hv;
}

// ---------------- fused mean pool + FC + softmax (batch is sorted) ----------------
__device__ __forceinline__ int lower_bound_i(const int* __restrict__ a, int n, int v) {
    int lo = 0, hi = n;
    while (lo < hi) {
        int mid = (lo + hi) >> 1;
        if (a[mid] < v) lo = mid + 1; else hi = mid;
    }
    return lo;
}

__global__ __launch_bounds__(256) void pool_fc_kernel(const ushort_t* __restrict__ hhi,
                                                      const int* __restrict__ batch,
                                                      int N,
                                                      const float* __restrict__ Wfc,
                                                      const float* __restrict__ bfc,
                                                      float* __restrict__ out) {
    __shared__ float red0[256];
    __shared__ float red1[256];
    int g = blockIdx.x;
    int c = threadIdx.x;                       // stored col
    int i = c & 63;
    int o = (c & ~63) | ((i & 3) << 4) | (i >> 2);   // orig col
    int beg = lower_bound_i(batch, N, g);
    int end = lower_bound_i(batch, N, g + 1);
    float sum = 0.f;
    for (int n = beg; n < end; ++n)
        sum += bf2f(hhi[(size_t)n * 256 + c]);
    float cnt = (float)(end - beg);
    float v = sum / fmaxf(cnt, 1.0f);
    red0[c] = v * Wfc[o * 2 + 0];
    red1[c] = v * Wfc[o * 2 + 1];
    __syncthreads();
    for (int off = 128; off > 0; off >>= 1) {
        if (c < off) {
            red0[c] += red0[c + off];
            red1[c] += red1[c + off];
        }
        __syncthreads();
    }
    if (c == 0) {
        float l0 = red0[0] + bfc[0];
        float l1 = red1[0] + bfc[1];
        float mx = fmaxf(l0, l1);
        float e0 = expf(l0 - mx), e1 = expf(l1 - mx);
        float s = e0 + e1;
        out[g * 2 + 0] = e0 / s;
        out[g * 2 + 1] = e1 / s;
    }
}

// ---------------- launch ----------------
extern "C" void kernel_launch(void* const* d_in, const int* in_sizes, int n_in,
                              void* d_out, int out_size, void* d_ws, size_t ws_size,
                              hipStream_t stream) {
    const float* x    = (const float*)d_in[0];
    const int*   eidx = (const int*)d_in[1];
    const int*   batch= (const int*)d_in[2];
    const float* Wl[3]  = {(const float*)d_in[3], (const float*)d_in[7],  (const float*)d_in[11]};
    const float* asl[3] = {(const float*)d_in[4], (const float*)d_in[8],  (const float*)d_in[12]};
    const float* adl[3] = {(const float*)d_in[5], (const float*)d_in[9],  (const float*)d_in[13]};
    const float* bl[3]  = {(const float*)d_in[6], (const float*)d_in[10], (const float*)d_in[14]};
    const float* Wfc = (const float*)d_in[15];
    const float* bfc = (const float*)d_in[16];
    float* out = (float*)d_out;

    const int N   = in_sizes[2];
    const int E   = in_sizes[1] / 2;
    const int DIN = in_sizes[0] / N;   // 128
    const int DH  = 256;
    const int G   = 512;
    const int* esrc = eidx;
    const int* edst = eidx + E;

    char* ws = (char*)d_ws;
    size_t off = 0;
    const size_t featHalf = (size_t)N * DH * sizeof(ushort_t);         // 25.6 MB
    unsigned char* hb = (unsigned char*)(ws + off); off += (size_t)N * DH;  // fp8, 12.8 MB
    ushort_t* ghi    = (ushort_t*)(ws + off); off += featHalf;         // gat out (bf16, stored order)
    ushort_t* xhi    = (ushort_t*)(ws + off); off += (size_t)N * DIN * sizeof(ushort_t);
    ushort_t* xlo    = (ushort_t*)(ws + off); off += (size_t)N * DIN * sizeof(ushort_t);
    float*    asA    = (float*)(ws + off); off += (size_t)N * sizeof(float);
    float*    adA    = (float*)(ws + off); off += (size_t)N * sizeof(float);
    float*    asB    = (float*)(ws + off); off += (size_t)N * sizeof(float);
    float*    adB    = (float*)(ws + off); off += (size_t)N * sizeof(float);
    int*      deg    = (int*)(ws + off);   off += (size_t)N * sizeof(int);
    int*      excl   = (int*)(ws + off);   off += (size_t)N * sizeof(int);
    int*      rowptr = (int*)(ws + off);   off += (size_t)(N + 1) * sizeof(int);
    int*      cursor = (int*)(ws + off);   off += (size_t)N * sizeof(int);
    int*      bsum   = (int*)(ws + off);   off += 1024;
    int*      csrsrc = (int*)(ws + off);   off += (size_t)E * sizeof(int);
    ushort_t* B1h    = (ushort_t*)(ws + off); off += (size_t)128 * 256 * sizeof(ushort_t);
    ushort_t* B1l    = (ushort_t*)(ws + off); off += (size_t)128 * 256 * sizeof(ushort_t);
    ushort_t* B2h    = (ushort_t*)(ws + off); off += (size_t)256 * 256 * sizeof(ushort_t);
    ushort_t* B2l    = (ushort_t*)(ws + off); off += (size_t)256 * 256 * sizeof(ushort_t);
    ushort_t* B3h    = (ushort_t*)(ws + off); off += (size_t)256 * 256 * sizeof(ushort_t);
    ushort_t* B3l    = (ushort_t*)(ws + off); off += (size_t)256 * 256 * sizeof(ushort_t);

    const int nbN = (N + 255) / 256;

    // ---- prep: deg/alphaA zero + x split + all W splits (coalesced) ----
    prep_kernel<<<((size_t)N * DIN + 255) / 256, 256, 0, stream>>>(
        x, xhi, xlo, deg, asA, adA, Wl[0], Wl[1], Wl[2],
        B1h, B1l, B2h, B2l, B3h, B3l, N * DIN, N);

    // ---- build CSR by dst (R13-proven single-phase) ----
    count_kernel<<<(E + 255) / 256, 256, 0, stream>>>(edst, deg, E);
    scan1_kernel<<<nbN, 256, 0, stream>>>(deg, excl, bsum, N);
    scan2_kernel<<<1, 256, 0, stream>>>(bsum, nbN);
    scan3_kernel<<<nbN, 256, 0, stream>>>(excl, bsum, rowptr, cursor, N, E);
    scatter_kernel<<<(E + 255) / 256, 256, 0, stream>>>(esrc, edst, cursor, csrsrc, E);

    const ushort_t* Bh[3]  = {B1h, B2h, B3h};
    const ushort_t* Blp[3] = {B1l, B2l, B3l};
    float* asCur[3] = {asA, asB, asA};
    float* adCur[3] = {adA, adB, adA};
    float* asNext[3] = {asB, asA, asB};   // zeroed by gat of this layer
    float* adNext[3] = {adB, adA, adB};

    dim3 ggrid((N + 127) / 128, 2);
    for (int layer = 0; layer < 3; ++layer) {
        if (layer == 0) {
            gemm_mfma<4, true, true><<<ggrid, 256, 0, stream>>>(xhi, xlo, Bh[0], Blp[0], hb,
                                                                asl[0], adl[0], asCur[0], adCur[0], N);
        } else {
            gemm_mfma<8, false, false><<<ggrid, 256, 0, stream>>>(ghi, nullptr, Bh[layer], Blp[layer], hb,
                                                                  asl[layer], adl[layer],
                                                                  asCur[layer], adCur[layer], N);
        }

        gat_fused_kernel<<<(N + 3) / 4, 256, 0, stream>>>(hb, asCur[layer], adCur[layer],
                                                          rowptr, csrsrc, bl[layer], ghi,
                                                          asNext[layer], adNext[layer], N);
    }

    pool_fc_kernel<<<G, 256, 0, stream>>>(ghi, batch, N, Wfc, bfc, out);
}